// Round 6
// baseline (329.294 us; speedup 1.0000x reference)
//
#include <hip/hip_runtime.h>

#define NB 8
#define NS 2048
#define ND 256
#define NH 4
#define NHD 64
#define ND2 512
#define NM (NB * NS)
#define PITCH 72            // padded LDS row pitch for Pl (bf16 elems)
#define C1 0.18033688f      // 0.125 * log2(e), prefolded into Q weights/bias

typedef __attribute__((ext_vector_type(8))) short          bf16x8;
typedef __attribute__((ext_vector_type(4))) float          f32x4;
typedef unsigned short ushort_t;
typedef unsigned int   uint_t;

#define MFMA16(a, b, c) __builtin_amdgcn_mfma_f32_16x16x32_bf16(a, b, c, 0, 0, 0)

// pack two fp32 -> packed bf16 pair (round-to-nearest-ish via +0x8000)
static __device__ inline uint_t pack2bf(float a, float b) {
    union { float f; uint_t u; } x, y; x.f = a; y.f = b;
    return __builtin_amdgcn_perm(y.u + 0x8000u, x.u + 0x8000u, 0x07060302u);
}
static __device__ inline ushort_t f2bf(float f) {
    union { float f; uint_t u; } x; x.f = f;
    return (ushort_t)((x.u + 0x7FFFu + ((x.u >> 16) & 1u)) >> 16);
}

// async global->LDS DMA, 16B/lane; LDS base wave-uniform, lane i -> base+i*16
static __device__ inline void gl_lds(const ushort_t* g, ushort_t* l) {
    __builtin_amdgcn_global_load_lds(
        (const __attribute__((address_space(1))) void*)g,
        (__attribute__((address_space(3))) void*)l, 16, 0, 0);
}

// ---------------------------------------------------------------------------
// prep: fp32 -> bf16 convert for desc / source
// ---------------------------------------------------------------------------
__global__ __launch_bounds__(256) void convert_acts(
    const float* __restrict__ d, const float* __restrict__ s,
    ushort_t* __restrict__ db, ushort_t* __restrict__ sb)
{
    const float* src = blockIdx.y ? s : d;
    ushort_t* dst    = blockIdx.y ? sb : db;
    const size_t i = ((size_t)blockIdx.x * 256 + threadIdx.x) * 4;
    float4 v = *(const float4*)(src + i);
    uint2 pv;
    pv.x = pack2bf(v.x, v.y);
    pv.y = pack2bf(v.z, v.w);
    *(uint2*)(dst + i) = pv;
}

// ---------------------------------------------------------------------------
// prep: W[K][N] fp32 -> bf16 WT[N][K]; case 0 (Q) pre-scaled by C1
// ---------------------------------------------------------------------------
__global__ __launch_bounds__(256) void transpose_w(
    const float* q, const float* k, const float* v, const float* m1,
    ushort_t* qt, ushort_t* kt, ushort_t* vt, ushort_t* m1t)
{
    const float* src; ushort_t* dst; int K, N; float sc = 1.0f;
    switch (blockIdx.y) {
        case 0: src = q;  dst = qt;  K = 256; N = 256; sc = C1; break;
        case 1: src = k;  dst = kt;  K = 256; N = 256; break;
        case 2: src = v;  dst = vt;  K = 256; N = 256; break;
        default: src = m1; dst = m1t; K = 512; N = 256; break;
    }
    const int idx = blockIdx.x * 256 + threadIdx.x;
    if (idx >= N * (K >> 3)) return;
    const int ksh = (K == 512) ? 6 : 5;
    const int n  = idx >> ksh;
    const int kc = (idx & ((1 << ksh) - 1)) << 3;
    float f[8];
#pragma unroll
    for (int j = 0; j < 8; j++) f[j] = src[(size_t)(kc + j) * N + n] * sc;
    uint4 pk;
    pk.x = pack2bf(f[0], f[1]);
    pk.y = pack2bf(f[2], f[3]);
    pk.z = pack2bf(f[4], f[5]);
    pk.w = pack2bf(f[6], f[7]);
    *(uint4*)(dst + (size_t)n * K + kc) = pk;
}

// ---------------------------------------------------------------------------
// prep: fused MLP0 weight. h = desc@m0a + ctx@F + bias', F = o_w@m0b,
// BN affine (A[n] = g/sqrt(v+eps)) folded into weights and bias.
// m0fT bf16 [n(512)][k(512)]: k<256 -> A*m0_w[k][n]; k>=256 -> A*F[k-256][n].
// biasf[n] = (m0_b[n] + o_b@m0b[:,n] - bn_m[n])*A + bn_b[n].
// grid 512 (=n), 256 threads (=i).
// ---------------------------------------------------------------------------
__global__ __launch_bounds__(256) void fuse_w(
    const float* __restrict__ o_w, const float* __restrict__ o_b,
    const float* __restrict__ m0_w, const float* __restrict__ m0_b,
    const float* __restrict__ bng, const float* __restrict__ bnb,
    const float* __restrict__ bnm, const float* __restrict__ bnv,
    ushort_t* __restrict__ m0fT, float* __restrict__ biasf)
{
    __shared__ float red[256];
    const int n = blockIdx.x;
    const int i = threadIdx.x;
    const float A = bng[n] * rsqrtf(bnv[n] + 1e-5f);
    float f = 0.f;
    for (int j = 0; j < 256; j++)
        f += o_w[i * 256 + j] * m0_w[(size_t)(256 + j) * 512 + n];
    m0fT[(size_t)n * 512 + 256 + i] = f2bf(f * A);
    m0fT[(size_t)n * 512 + i]       = f2bf(m0_w[(size_t)i * 512 + n] * A);
    red[i] = o_b[i] * m0_w[(size_t)(256 + i) * 512 + n];
    __syncthreads();
    for (int s = 128; s > 0; s >>= 1) {
        if (i < s) red[i] += red[i + s];
        __syncthreads();
    }
    if (i == 0) biasf[n] = (m0_b[n] + red[0] - bnm[n]) * A + bnb[n];
}

// ---------------------------------------------------------------------------
// prep: mask -> additive bias (0 / -1e9)
// ---------------------------------------------------------------------------
__global__ __launch_bounds__(256) void make_mbias(
    const int* __restrict__ mask, float* __restrict__ mb)
{
    const int i = blockIdx.x * 256 + threadIdx.x;
    mb[i] = mask[i] ? 0.0f : -1e9f;
}

// ---------------------------------------------------------------------------
// GEMM core: 64(M) x 128(N) tile, BK=64, 4 waves, wave-tile 32x64 (2x4 MFMA).
// DMA staging into swizzled LDS [kgrp][row][8]. A split at K0 col boundary.
// NAT=false: acc = WT-frag x Act-frag (D: row=channel, col=token)
// NAT=true : acc = Act-frag x WT-frag (D: row=token, col=channel)
// ---------------------------------------------------------------------------
template <bool NAT>
static __device__ inline void gemm_core(
    const ushort_t* __restrict__ A0, const ushort_t* __restrict__ A1, int K0,
    const ushort_t* __restrict__ WT, int K, int row0, int n0,
    ushort_t* Al, ushort_t* Wl, f32x4 acc[2][4])
{
    const int t  = threadIdx.x;
    const int w  = t >> 6;
    const int lq = t & 15;
    const int lg = (t & 63) >> 4;
    const int wm = (w & 1) << 5;
    const int wn = (w >> 1) << 6;

    for (int kt = 0; kt < K; kt += 64) {
        const bool first = (kt < K0);
        const ushort_t* Asrc = first ? A0 : A1;
        const int lda = first ? K0 : (K - K0);
        const int kb  = first ? kt : (kt - K0);
        __syncthreads();
#pragma unroll
        for (int r = 0; r < 2; r++) {            // Act 64x64: 512 chunks
            const int p = r * 256 + t;
            const int row = p & 63, kg = p >> 6;
            gl_lds(Asrc + (size_t)(row0 + row) * lda + kb + kg * 8,
                   &Al[(r * 256 + w * 64) * 8]);
        }
#pragma unroll
        for (int r = 0; r < 4; r++) {            // WT 128x64: 1024 chunks
            const int p = r * 256 + t;
            const int row = p & 127, kg = p >> 7;
            gl_lds(WT + (size_t)(n0 + row) * K + kt + kg * 8,
                   &Wl[(r * 256 + w * 64) * 8]);
        }
        __syncthreads();
#pragma unroll
        for (int kc = 0; kc < 2; kc++) {
            bf16x8 af[2], wf[4];
#pragma unroll
            for (int mt = 0; mt < 2; mt++)
                af[mt] = *(const bf16x8*)&Al[(((kc * 4 + lg) << 6) + wm + mt * 16 + lq) * 8];
#pragma unroll
            for (int nt = 0; nt < 4; nt++)
                wf[nt] = *(const bf16x8*)&Wl[(((kc * 4 + lg) << 7) + wn + nt * 16 + lq) * 8];
#pragma unroll
            for (int mt = 0; mt < 2; mt++)
#pragma unroll
                for (int nt = 0; nt < 4; nt++) {
                    if (NAT)
                        acc[mt][nt] = MFMA16(af[mt], wf[nt], acc[mt][nt]);
                    else
                        acc[mt][nt] = MFMA16(wf[nt], af[mt], acc[mt][nt]);
                }
        }
    }
}

// ---------------------------------------------------------------------------
// fused QKV projections. grid (2, NM/64, 3); z=0: Q (scaled, head-major),
// z=1: K (head-major), z=2: V (natural ops, head-transposed [b][h][dv][s]).
// ---------------------------------------------------------------------------
__global__ __launch_bounds__(256) void qkv_mfma(
    const ushort_t* __restrict__ desc_bf, const ushort_t* __restrict__ src_bf,
    const ushort_t* __restrict__ qwT, const ushort_t* __restrict__ kwT,
    const ushort_t* __restrict__ vwT,
    const float* __restrict__ q_b, const float* __restrict__ k_b,
    const float* __restrict__ v_b,
    ushort_t* __restrict__ qbf, ushort_t* __restrict__ kbf,
    ushort_t* __restrict__ vtbf)
{
    __shared__ ushort_t Al[64 * 64];
    __shared__ ushort_t Wl[128 * 64];
    const int t  = threadIdx.x;
    const int w  = t >> 6;
    const int lq = t & 15;
    const int lg = (t & 63) >> 4;
    const int wm = (w & 1) << 5;
    const int wn = (w >> 1) << 6;
    const int n0   = blockIdx.x << 7;
    const int row0 = blockIdx.y << 6;
    const int z    = blockIdx.z;

    f32x4 acc[2][4];
#pragma unroll
    for (int mt = 0; mt < 2; mt++)
#pragma unroll
        for (int nt = 0; nt < 4; nt++) acc[mt][nt] = (f32x4){0.f, 0.f, 0.f, 0.f};

    if (z == 2) {
        gemm_core<true>(src_bf, src_bf, ND, vwT, ND, row0, n0, Al, Wl, acc);
#pragma unroll
        for (int nt = 0; nt < 4; nt++) {
            const int ch = n0 + wn + nt * 16 + lq;
            const int h = ch >> 6, dv = ch & 63;
            const float bs = v_b[ch];
#pragma unroll
            for (int mt = 0; mt < 2; mt++) {
                const int tok0 = row0 + wm + mt * 16 + lg * 4;
                const int b = tok0 >> 11, s = tok0 & 2047;
                uint2 pv;
                pv.x = pack2bf(acc[mt][nt][0] + bs, acc[mt][nt][1] + bs);
                pv.y = pack2bf(acc[mt][nt][2] + bs, acc[mt][nt][3] + bs);
                *(uint2*)(vtbf + ((size_t)(b * NH + h) * NHD + dv) * NS + s) = pv;
            }
        }
    } else {
        const ushort_t* A = z ? src_bf : desc_bf;
        const ushort_t* W = z ? kwT : qwT;
        const float* bias = z ? k_b : q_b;
        ushort_t* outp    = z ? kbf : qbf;
        const float bsc   = z ? 1.0f : C1;
        gemm_core<false>(A, A, ND, W, ND, row0, n0, Al, Wl, acc);
#pragma unroll
        for (int nt = 0; nt < 4; nt++) {
            const int nb = n0 + wn + nt * 16 + lg * 4;
            const int h = nb >> 6, d = nb & 63;
            f32x4 b4 = *(const f32x4*)(bias + nb);
#pragma unroll
            for (int mt = 0; mt < 2; mt++) {
                const int tok = row0 + wm + mt * 16 + lq;
                const int b = tok >> 11, s = tok & 2047;
                uint2 pv;
                pv.x = pack2bf(acc[mt][nt][0] + b4[0] * bsc,
                               acc[mt][nt][1] + b4[1] * bsc);
                pv.y = pack2bf(acc[mt][nt][2] + b4[2] * bsc,
                               acc[mt][nt][3] + b4[3] * bsc);
                *(uint2*)(outp + ((size_t)(b * NH + h) * NS + s) * NHD + d) = pv;
            }
        }
    }
}

// ---------------------------------------------------------------------------
// MLP0 (fused with out-proj + BN): h = relu([desc|ctx] @ m0fT^T + biasf)
// grid (4, NM/64). bf16 out row-major [tok][512].
// ---------------------------------------------------------------------------
__global__ __launch_bounds__(256) void mlp0_mfma(
    const ushort_t* __restrict__ desc_bf, const ushort_t* __restrict__ ctx_bf,
    const ushort_t* __restrict__ m0fT, const float* __restrict__ biasf,
    ushort_t* __restrict__ hbuf)
{
    __shared__ ushort_t Al[64 * 64];
    __shared__ ushort_t Wl[128 * 64];
    const int t  = threadIdx.x;
    const int w  = t >> 6;
    const int lq = t & 15;
    const int lg = (t & 63) >> 4;
    const int wm = (w & 1) << 5;
    const int wn = (w >> 1) << 6;
    const int n0   = blockIdx.x << 7;
    const int row0 = blockIdx.y << 6;

    f32x4 acc[2][4];
#pragma unroll
    for (int mt = 0; mt < 2; mt++)
#pragma unroll
        for (int nt = 0; nt < 4; nt++) acc[mt][nt] = (f32x4){0.f, 0.f, 0.f, 0.f};

    gemm_core<false>(desc_bf, ctx_bf, ND, m0fT, ND2, row0, n0, Al, Wl, acc);

#pragma unroll
    for (int nt = 0; nt < 4; nt++) {
        const int nb = n0 + wn + nt * 16 + lg * 4;
        f32x4 b4 = *(const f32x4*)(biasf + nb);
#pragma unroll
        for (int mt = 0; mt < 2; mt++) {
            const int tok = row0 + wm + mt * 16 + lq;
            float r[4];
#pragma unroll
            for (int j = 0; j < 4; j++) r[j] = fmaxf(acc[mt][nt][j] + b4[j], 0.0f);
            uint2 pv;
            pv.x = pack2bf(r[0], r[1]);
            pv.y = pack2bf(r[2], r[3]);
            *(uint2*)(hbuf + (size_t)tok * ND2 + nb) = pv;
        }
    }
}

// ---------------------------------------------------------------------------
// MLP1: out = h @ m1T^T + m1_b, fp32 out. grid (2, NM/64).
// ---------------------------------------------------------------------------
__global__ __launch_bounds__(256) void mlp1_mfma(
    const ushort_t* __restrict__ hbuf, const ushort_t* __restrict__ m1T,
    const float* __restrict__ m1_b, float* __restrict__ out)
{
    __shared__ ushort_t Al[64 * 64];
    __shared__ ushort_t Wl[128 * 64];
    const int t  = threadIdx.x;
    const int w  = t >> 6;
    const int lq = t & 15;
    const int lg = (t & 63) >> 4;
    const int wm = (w & 1) << 5;
    const int wn = (w >> 1) << 6;
    const int n0   = blockIdx.x << 7;
    const int row0 = blockIdx.y << 6;

    f32x4 acc[2][4];
#pragma unroll
    for (int mt = 0; mt < 2; mt++)
#pragma unroll
        for (int nt = 0; nt < 4; nt++) acc[mt][nt] = (f32x4){0.f, 0.f, 0.f, 0.f};

    gemm_core<false>(hbuf, hbuf, ND2, m1T, ND2, row0, n0, Al, Wl, acc);

#pragma unroll
    for (int nt = 0; nt < 4; nt++) {
        const int nb = n0 + wn + nt * 16 + lg * 4;
        f32x4 b4 = *(const f32x4*)(m1_b + nb);
#pragma unroll
        for (int mt = 0; mt < 2; mt++) {
            const int tok = row0 + wm + mt * 16 + lq;
            f32x4 o4;
#pragma unroll
            for (int j = 0; j < 4; j++) o4[j] = acc[mt][nt][j] + b4[j];
            *(f32x4*)(out + (size_t)tok * ND + nb) = o4;
        }
    }
}

// ---------------------------------------------------------------------------
// MFMA flash cross-attention v3. Grid (NS/64, H, B) = 1024 blocks (4/CU),
// 4 waves, wave owns 16 q rows. Scale prefolded into Q; mask is additive
// float bias; no running max (scores bounded, exact). Per 64-key chunk:
// S^T = K.Q^T -> p = exp2(s+mb) -> P bf16 via per-wave LDS -> ctx^T += V^T.P.
// ---------------------------------------------------------------------------
__global__ __launch_bounds__(256) void attn_mfma(
    const ushort_t* __restrict__ qbf, const ushort_t* __restrict__ kbf,
    const ushort_t* __restrict__ vtbf, const float* __restrict__ mbias,
    ushort_t* __restrict__ ctxb)
{
    __shared__ ushort_t Kl[64 * 64];        // swizzled [kgrp(8)][row(64)][8]
    __shared__ ushort_t Vl[64 * 64];
    __shared__ ushort_t Pl[4][16 * PITCH];  // per-wave [q(16)][key(64) padded]

    const int t  = threadIdx.x;
    const int w  = t >> 6;
    const int lq = t & 15;
    const int lg = (t & 63) >> 4;
    const int qb = blockIdx.x;
    const int h  = blockIdx.y;
    const int b  = blockIdx.z;
    const int bh = b * NH + h;

    const ushort_t* qh = qbf + (size_t)bh * NS * NHD;
    const ushort_t* kh = kbf + (size_t)bh * NS * NHD;
    const ushort_t* vh = vtbf + (size_t)bh * NHD * NS;
    const float* mrow = mbias + b * NS;
    const int qrow0 = qb * 64 + w * 16;

    // Q fragments (B-operand): lane holds Q[q=lq][d = dh*32 + lg*8 ..+8]
    bf16x8 qf[2];
#pragma unroll
    for (int dh = 0; dh < 2; dh++)
        qf[dh] = *(const bf16x8*)(qh + (size_t)(qrow0 + lq) * NHD + dh * 32 + lg * 8);

    f32x4 o[4];
#pragma unroll
    for (int dt = 0; dt < 4; dt++) o[dt] = (f32x4){0.f, 0.f, 0.f, 0.f};
    float l_run = 0.0f;

    for (int key0 = 0; key0 < NS; key0 += 64) {
        __syncthreads();  // prior chunk's LDS reads done before DMA overwrite
#pragma unroll
        for (int r = 0; r < 2; r++) {
            const int p = r * 256 + t;
            const int row = p & 63, kg = p >> 6;
            const int lb = (r * 256 + w * 64) * 8;
            gl_lds(kh + (size_t)(key0 + row) * NHD + kg * 8, &Kl[lb]);
            gl_lds(vh + (size_t)row * NS + key0 + kg * 8, &Vl[lb]);
        }
        __syncthreads();

        // S^T[key][q] = K.Q^T  (C-layout: col = q = lq, row = key)
        f32x4 st[4];
#pragma unroll
        for (int kt = 0; kt < 4; kt++) {
            bf16x8 ka0 = *(const bf16x8*)&Kl[(((0 * 4 + lg) << 6) + kt * 16 + lq) * 8];
            bf16x8 ka1 = *(const bf16x8*)&Kl[(((1 * 4 + lg) << 6) + kt * 16 + lq) * 8];
            f32x4 a = (f32x4){0.f, 0.f, 0.f, 0.f};
            a = MFMA16(ka0, qf[0], a);
            a = MFMA16(ka1, qf[1], a);
            st[kt] = a;
        }
        // softmax numerator (no max-subtract), mask via additive bias
        float ls = 0.0f;
#pragma unroll
        for (int kt = 0; kt < 4; kt++) {
            f32x4 mb = *(const f32x4*)(mrow + key0 + kt * 16 + lg * 4);
            float pr[4];
#pragma unroll
            for (int r = 0; r < 4; r++) {
                const float p = exp2f(st[kt][r] + mb[r]);
                ls += p;
                pr[r] = p;
            }
            uint2 pv;
            pv.x = pack2bf(pr[0], pr[1]);
            pv.y = pack2bf(pr[2], pr[3]);
            *(uint2*)&Pl[w][lq * PITCH + kt * 16 + lg * 4] = pv;
        }
        ls += __shfl_xor(ls, 16);
        ls += __shfl_xor(ls, 32);
        l_run += ls;

        // P B-fragments, then ctx^T[dv][q] += V^T.P
        bf16x8 pf[2];
#pragma unroll
        for (int kh2 = 0; kh2 < 2; kh2++)
            pf[kh2] = *(const bf16x8*)&Pl[w][lq * PITCH + kh2 * 32 + lg * 8];
#pragma unroll
        for (int dt = 0; dt < 4; dt++)
#pragma unroll
            for (int kh2 = 0; kh2 < 2; kh2++) {
                bf16x8 vf = *(const bf16x8*)
                    &Vl[(((kh2 * 4 + lg) << 6) + dt * 16 + lq) * 8];
                o[dt] = MFMA16(vf, pf[kh2], o[dt]);
            }
    }

    // epilogue: normalize, write bf16 ctx[token][256]
    const float li = 1.0f / l_run;
    const int tok = b * NS + qrow0 + lq;
#pragma unroll
    for (int dt = 0; dt < 4; dt++) {
        uint2 pv;
        pv.x = pack2bf(o[dt][0] * li, o[dt][1] * li);
        pv.y = pack2bf(o[dt][2] * li, o[dt][3] * li);
        *(uint2*)(ctxb + (size_t)tok * ND + h * NHD + dt * 16 + lg * 4) = pv;
    }
}

extern "C" void kernel_launch(void* const* d_in, const int* in_sizes, int n_in,
                              void* d_out, int out_size, void* d_ws, size_t ws_size,
                              hipStream_t stream)
{
    (void)in_sizes; (void)n_in; (void)out_size; (void)ws_size;
    const float* desc = (const float*)d_in[0];
    const float* srcp = (const float*)d_in[1];
    const int*   mask = (const int*)d_in[2];
    const float* q_w  = (const float*)d_in[3];
    const float* q_b  = (const float*)d_in[4];
    const float* k_w  = (const float*)d_in[5];
    const float* k_b  = (const float*)d_in[6];
    const float* v_w  = (const float*)d_in[7];
    const float* v_b  = (const float*)d_in[8];
    const float* o_w  = (const float*)d_in[9];
    const float* o_b  = (const float*)d_in[10];
    const float* m0_w = (const float*)d_in[11];
    const float* m0_b = (const float*)d_in[12];
    const float* bng  = (const float*)d_in[13];
    const float* bnb  = (const float*)d_in[14];
    const float* bnm  = (const float*)d_in[15];
    const float* bnv  = (const float*)d_in[16];
    const float* m1_w = (const float*)d_in[17];
    const float* m1_b = (const float*)d_in[18];
    float* out = (float*)d_out;

    // ws layout (~42 MB): 5 activation buffers of ASZ bf16 + weights/bias
    const size_t ASZ = (size_t)NM * ND;  // 4,194,304 elems
    ushort_t* desc_bf = (ushort_t*)d_ws;
    ushort_t* src_bf  = desc_bf + ASZ;
    ushort_t* qbf     = desc_bf + 2 * ASZ;
    ushort_t* kbf     = desc_bf + 3 * ASZ;
    ushort_t* vtbf    = desc_bf + 4 * ASZ;
    ushort_t* qwT     = desc_bf + 5 * ASZ;          // 65536
    ushort_t* kwT     = qwT + 65536;
    ushort_t* vwT     = kwT + 65536;
    ushort_t* m1T     = vwT + 65536;                // 131072
    ushort_t* m0fT    = m1T + 131072;               // 262144
    float*    biasf   = (float*)(m0fT + 262144);    // 512
    float*    mbias   = biasf + 512;                // 16384
    ushort_t* ctx_bf  = src_bf;   // src dead after QKV
    ushort_t* hbuf    = kbf;      // k+v dead after attention (16 MB span)

    const dim3 blk(256);

    convert_acts<<<dim3(ASZ / 1024, 2), blk, 0, stream>>>(desc, srcp, desc_bf, src_bf);
    transpose_w<<<dim3(64, 4), blk, 0, stream>>>(q_w, k_w, v_w, m1_w, qwT, kwT, vwT, m1T);
    fuse_w<<<dim3(512), blk, 0, stream>>>(o_w, o_b, m0_w, m0_b,
                                          bng, bnb, bnm, bnv, m0fT, biasf);
    make_mbias<<<dim3(NM * sizeof(int) / 4 / 256 / 16), blk, 0, stream>>>(mask, mbias);

    qkv_mfma<<<dim3(2, NM / 64, 3), blk, 0, stream>>>(
        desc_bf, src_bf, qwT, kwT, vwT, q_b, k_b, v_b, qbf, kbf, vtbf);
    attn_mfma<<<dim3(NS / 64, NH, NB), blk, 0, stream>>>(qbf, kbf, vtbf, mbias, ctx_bf);
    mlp0_mfma<<<dim3(4, NM / 64), blk, 0, stream>>>(desc_bf, ctx_bf, m0fT, biasf, hbuf);
    mlp1_mfma<<<dim3(2, NM / 64), blk, 0, stream>>>(hbuf, m1T, m1_b, out);
}

// Round 7
// 304.505 us; speedup vs baseline: 1.0814x; 1.0814x over previous
//
#include <hip/hip_runtime.h>

#define NB 8
#define NS 2048
#define ND 256
#define NH 4
#define NHD 64
#define ND2 512
#define NM (NB * NS)
#define PITCH 72            // padded LDS row pitch for Pl (bf16 elems)
#define C1 0.18033688f      // 0.125 * log2(e), prefolded into Q weights/bias

typedef __attribute__((ext_vector_type(8))) short          bf16x8;
typedef __attribute__((ext_vector_type(4))) float          f32x4;
typedef unsigned short ushort_t;
typedef unsigned int   uint_t;

#define MFMA16(a, b, c) __builtin_amdgcn_mfma_f32_16x16x32_bf16(a, b, c, 0, 0, 0)

static __device__ inline uint_t pack2bf(float a, float b) {
    union { float f; uint_t u; } x, y; x.f = a; y.f = b;
    return __builtin_amdgcn_perm(y.u + 0x8000u, x.u + 0x8000u, 0x07060302u);
}
static __device__ inline ushort_t f2bf(float f) {
    union { float f; uint_t u; } x; x.f = f;
    return (ushort_t)((x.u + 0x7FFFu + ((x.u >> 16) & 1u)) >> 16);
}

// ===========================================================================
// Fragment-major layout: matrix Mat[R][C] stored so that the MFMA fragment
// (lane lq=l&15 holds Mat[r16*16+lq][kc*32+(l>>4)*8+j], j=0..7) is one
// coalesced 16B/lane load:  elem = ((r16*(C/32)+kc)*64 + lane)*8 + j.
// Same geometry for A- and B-operands (HW-verified rounds 3-6).
// ===========================================================================

// ---------------------------------------------------------------------------
// prep: desc/src fp32 row-major -> frag-major bf16 (grid.y selects buffer)
// ---------------------------------------------------------------------------
__global__ __launch_bounds__(256) void conv_frag(
    const float* __restrict__ d, const float* __restrict__ s,
    ushort_t* __restrict__ df, ushort_t* __restrict__ sf)
{
    const float* src = blockIdx.y ? s : d;
    ushort_t* dst    = blockIdx.y ? sf : df;
    const int g = blockIdx.x * 256 + threadIdx.x;
    const int lane = g & 63, ci = g >> 6;
    const int kc = ci & 7, r16 = ci >> 3;       // C=256 -> 8 k-chunks
    const int row = r16 * 16 + (lane & 15);
    const int c0  = kc * 32 + (lane >> 4) * 8;
    const float* p = src + (size_t)row * ND + c0;
    float4 a = *(const float4*)p;
    float4 b = *(const float4*)(p + 4);
    uint4 pk;
    pk.x = pack2bf(a.x, a.y); pk.y = pack2bf(a.z, a.w);
    pk.z = pack2bf(b.x, b.y); pk.w = pack2bf(b.z, b.w);
    *(uint4*)(dst + (size_t)g * 8) = pk;
}

// ---------------------------------------------------------------------------
// prep: W[K][N] fp32 -> frag-major bf16 of W^T[N][K]; y=0 Q (scaled C1),
// y=1 K, y=2 V, y=3 m1.
// ---------------------------------------------------------------------------
__global__ __launch_bounds__(256) void wfrag(
    const float* q, const float* k, const float* v, const float* m1,
    ushort_t* qw, ushort_t* kw, ushort_t* vw, ushort_t* m1f)
{
    const float* src; ushort_t* dst; int K, N; float sc = 1.0f;
    switch (blockIdx.y) {
        case 0: src = q;  dst = qw;  K = 256; N = 256; sc = C1; break;
        case 1: src = k;  dst = kw;  K = 256; N = 256; break;
        case 2: src = v;  dst = vw;  K = 256; N = 256; break;
        default: src = m1; dst = m1f; K = 512; N = 256; break;
    }
    const int g = blockIdx.x * 256 + threadIdx.x;
    if (g >= (N * K) / 8) return;
    const int lane = g & 63, ci = g >> 6;
    const int lgck = (K == 512) ? 4 : 3;
    const int kc = ci & ((1 << lgck) - 1), n16 = ci >> lgck;
    const int n  = n16 * 16 + (lane & 15);
    const int k0 = kc * 32 + (lane >> 4) * 8;
    float f[8];
#pragma unroll
    for (int j = 0; j < 8; j++) f[j] = src[(size_t)(k0 + j) * N + n] * sc;
    uint4 pk;
    pk.x = pack2bf(f[0], f[1]); pk.y = pack2bf(f[2], f[3]);
    pk.z = pack2bf(f[4], f[5]); pk.w = pack2bf(f[6], f[7]);
    *(uint4*)(dst + (size_t)g * 8) = pk;
}

// emit one scalar into a frag-major W^T[N][C=512] buffer
static __device__ inline void femit(ushort_t* buf, int n, int k, float v) {
    const int kc = k >> 5;
    const int lane = (((k >> 3) & 3) << 4) | (n & 15);
    const int j = k & 7;
    buf[((size_t)(((n >> 4) * 16 + kc) * 64 + lane)) * 8 + j] = f2bf(v);
}

// ---------------------------------------------------------------------------
// prep: fused MLP0 weight (out-proj + BN folded), frag-major.
// h = desc@m0a + ctx@F + bias', F = o_w@m0b, A[n] = g/sqrt(v+eps).
// ---------------------------------------------------------------------------
__global__ __launch_bounds__(256) void fuse_w(
    const float* __restrict__ o_w, const float* __restrict__ o_b,
    const float* __restrict__ m0_w, const float* __restrict__ m0_b,
    const float* __restrict__ bng, const float* __restrict__ bnb,
    const float* __restrict__ bnm, const float* __restrict__ bnv,
    ushort_t* __restrict__ m0fF, float* __restrict__ biasf)
{
    __shared__ float red[256];
    const int n = blockIdx.x;
    const int i = threadIdx.x;
    const float A = bng[n] * rsqrtf(bnv[n] + 1e-5f);
    float f = 0.f;
    for (int j = 0; j < 256; j++)
        f += o_w[i * 256 + j] * m0_w[(size_t)(256 + j) * 512 + n];
    femit(m0fF, n, 256 + i, f * A);
    femit(m0fF, n, i, m0_w[(size_t)i * 512 + n] * A);
    red[i] = o_b[i] * m0_w[(size_t)(256 + i) * 512 + n];
    __syncthreads();
    for (int s = 128; s > 0; s >>= 1) {
        if (i < s) red[i] += red[i + s];
        __syncthreads();
    }
    if (i == 0) biasf[n] = (m0_b[n] + red[0] - bnm[n]) * A + bnb[n];
}

__global__ __launch_bounds__(256) void make_mbias(
    const int* __restrict__ mask, float* __restrict__ mb)
{
    const int i = blockIdx.x * 256 + threadIdx.x;
    mb[i] = mask[i] ? 0.0f : -1e9f;
}

// ---------------------------------------------------------------------------
// GEMM core: all-global frag-major, NO LDS, NO barriers. Wave-tile 32 tok x
// 64 ch (2x4 MFMA per kc). KC = K/32 total chunks; AK = chunks per A buffer
// (concat split). NAT=false: D row=channel,col=token; NAT=true: row=token.
// ---------------------------------------------------------------------------
template <int KC, int AK, bool NAT>
static __device__ inline void core(
    const ushort_t* __restrict__ A0, const ushort_t* __restrict__ A1,
    const ushort_t* __restrict__ WF, int t16, int n16, f32x4 acc[2][4])
{
    const int lane = threadIdx.x & 63;
#pragma unroll
    for (int kc = 0; kc < KC; kc++) {
        const ushort_t* Ab = (kc < AK) ? A0 : A1;
        const int kca = (kc < AK) ? kc : kc - AK;
        bf16x8 af[2], wf[4];
#pragma unroll
        for (int mt = 0; mt < 2; mt++)
            af[mt] = *(const bf16x8*)(Ab + ((size_t)((t16 + mt) * AK + kca) * 64 + lane) * 8);
#pragma unroll
        for (int nt = 0; nt < 4; nt++)
            wf[nt] = *(const bf16x8*)(WF + ((size_t)((n16 + nt) * KC + kc) * 64 + lane) * 8);
#pragma unroll
        for (int mt = 0; mt < 2; mt++)
#pragma unroll
            for (int nt = 0; nt < 4; nt++) {
                if (NAT) acc[mt][nt] = MFMA16(af[mt], wf[nt], acc[mt][nt]);
                else     acc[mt][nt] = MFMA16(wf[nt], af[mt], acc[mt][nt]);
            }
    }
}

// ---------------------------------------------------------------------------
// fused QKV. grid (4 heads, NM/128, 3); block 64ch x 128tok, 4 waves.
// z=0: Q (C1-scaled) -> qF frag-major; z=1: K -> kF; z=2: V -> vF (V^T frags).
// ---------------------------------------------------------------------------
__global__ __launch_bounds__(256, 4) void qkv_frag(
    const ushort_t* __restrict__ descF, const ushort_t* __restrict__ srcF,
    const ushort_t* __restrict__ qwF, const ushort_t* __restrict__ kwF,
    const ushort_t* __restrict__ vwF,
    const float* __restrict__ q_b, const float* __restrict__ k_b,
    const float* __restrict__ v_b,
    ushort_t* __restrict__ qF, ushort_t* __restrict__ kF,
    ushort_t* __restrict__ vF)
{
    const int t = threadIdx.x, w = t >> 6, lane = t & 63;
    const int lq = t & 15, lg = lane >> 4;
    const int h    = blockIdx.x;
    const int tok0 = (blockIdx.y << 7) + (w << 5);
    const int t16  = tok0 >> 4, n16 = h << 2;
    const int z    = blockIdx.z;

    f32x4 acc[2][4];
#pragma unroll
    for (int mt = 0; mt < 2; mt++)
#pragma unroll
        for (int nt = 0; nt < 4; nt++) acc[mt][nt] = (f32x4){0.f, 0.f, 0.f, 0.f};

    if (z == 2) {
        core<8, 8, true>(srcF, srcF, vwF, t16, n16, acc);
        // D: row = token (4lg+r within mt group), col = dv = lq (+nt*16)
#pragma unroll
        for (int nt = 0; nt < 4; nt++) {
            const int dvh = nt * 16 + lq;
            const float bs = v_b[h * 64 + dvh];
#pragma unroll
            for (int mt = 0; mt < 2; mt++) {
                const int tok = tok0 + mt * 16 + lg * 4;
                const int b = tok >> 11, s0 = tok & 2047;
                const int bh = b * NH + h;
                uint2 pv;
                pv.x = pack2bf(acc[mt][nt][0] + bs, acc[mt][nt][1] + bs);
                pv.y = pack2bf(acc[mt][nt][2] + bs, acc[mt][nt][3] + bs);
                const size_t e = (size_t)bh * 131072 +
                    ((size_t)((dvh >> 4) * 64 + (s0 >> 5)) * 64 +
                     (((s0 >> 3) & 3) * 16 + (dvh & 15))) * 8 + (s0 & 7);
                *(uint2*)(vF + e) = pv;
            }
        }
    } else {
        const ushort_t* A = z ? srcF : descF;
        const ushort_t* W = z ? kwF : qwF;
        const float* bias = z ? k_b : q_b;
        ushort_t* dst     = z ? kF : qF;
        const float bsc   = z ? 1.0f : C1;
        core<8, 8, false>(A, A, W, t16, n16, acc);
        // D: row = channel d0+r, col = token = lq
#pragma unroll
        for (int nt = 0; nt < 4; nt++) {
            const int d0 = nt * 16 + lg * 4;
            f32x4 b4 = *(const f32x4*)(bias + h * 64 + d0);
#pragma unroll
            for (int mt = 0; mt < 2; mt++) {
                const int tok = tok0 + mt * 16 + lq;
                const int b = tok >> 11, s = tok & 2047;
                const int bh = b * NH + h;
                uint2 pv;
                pv.x = pack2bf(acc[mt][nt][0] + b4[0] * bsc,
                               acc[mt][nt][1] + b4[1] * bsc);
                pv.y = pack2bf(acc[mt][nt][2] + b4[2] * bsc,
                               acc[mt][nt][3] + b4[3] * bsc);
                const size_t e = (size_t)bh * 131072 +
                    ((size_t)((s >> 4) * 2 + (d0 >> 5)) * 64 +
                     (((d0 >> 3) & 3) * 16 + lq)) * 8 + (d0 & 7);
                *(uint2*)(dst + e) = pv;
            }
        }
    }
}

// ---------------------------------------------------------------------------
// MLP0 (out-proj+BN fused): h = relu([desc|ctx]@m0f + biasf) -> hF frag-major
// grid (8, NM/128).
// ---------------------------------------------------------------------------
__global__ __launch_bounds__(256, 4) void mlp0_frag(
    const ushort_t* __restrict__ descF, const ushort_t* __restrict__ ctxF,
    const ushort_t* __restrict__ m0fF, const float* __restrict__ biasf,
    ushort_t* __restrict__ hF)
{
    const int t = threadIdx.x, w = t >> 6;
    const int lq = t & 15, lg = (t & 63) >> 4;
    const int n0   = blockIdx.x << 6;
    const int tok0 = (blockIdx.y << 7) + (w << 5);
    const int t16  = tok0 >> 4, n16 = n0 >> 4;

    f32x4 acc[2][4];
#pragma unroll
    for (int mt = 0; mt < 2; mt++)
#pragma unroll
        for (int nt = 0; nt < 4; nt++) acc[mt][nt] = (f32x4){0.f, 0.f, 0.f, 0.f};

    core<16, 8, false>(descF, ctxF, m0fF, t16, n16, acc);

#pragma unroll
    for (int nt = 0; nt < 4; nt++) {
        const int c0 = n0 + nt * 16 + lg * 4;
        f32x4 b4 = *(const f32x4*)(biasf + c0);
#pragma unroll
        for (int mt = 0; mt < 2; mt++) {
            const int tok = tok0 + mt * 16 + lq;
            uint2 pv;
            pv.x = pack2bf(fmaxf(acc[mt][nt][0] + b4[0], 0.f),
                           fmaxf(acc[mt][nt][1] + b4[1], 0.f));
            pv.y = pack2bf(fmaxf(acc[mt][nt][2] + b4[2], 0.f),
                           fmaxf(acc[mt][nt][3] + b4[3], 0.f));
            const size_t e = ((size_t)((tok >> 4) * 16 + (c0 >> 5)) * 64 +
                              (((c0 >> 3) & 3) * 16 + lq)) * 8 + (c0 & 7);
            *(uint2*)(hF + e) = pv;
        }
    }
}

// ---------------------------------------------------------------------------
// MLP1: out = hF @ m1 + m1_b, fp32 row-major. grid (4, NM/128).
// ---------------------------------------------------------------------------
__global__ __launch_bounds__(256, 4) void mlp1_frag(
    const ushort_t* __restrict__ hF, const ushort_t* __restrict__ m1F,
    const float* __restrict__ m1_b, float* __restrict__ out)
{
    const int t = threadIdx.x, w = t >> 6;
    const int lq = t & 15, lg = (t & 63) >> 4;
    const int n0   = blockIdx.x << 6;
    const int tok0 = (blockIdx.y << 7) + (w << 5);
    const int t16  = tok0 >> 4, n16 = n0 >> 4;

    f32x4 acc[2][4];
#pragma unroll
    for (int mt = 0; mt < 2; mt++)
#pragma unroll
        for (int nt = 0; nt < 4; nt++) acc[mt][nt] = (f32x4){0.f, 0.f, 0.f, 0.f};

    core<16, 16, false>(hF, hF, m1F, t16, n16, acc);

#pragma unroll
    for (int nt = 0; nt < 4; nt++) {
        const int c0 = n0 + nt * 16 + lg * 4;
        f32x4 b4 = *(const f32x4*)(m1_b + c0);
#pragma unroll
        for (int mt = 0; mt < 2; mt++) {
            const int tok = tok0 + mt * 16 + lq;
            f32x4 o4;
#pragma unroll
            for (int j = 0; j < 4; j++) o4[j] = acc[mt][nt][j] + b4[j];
            *(f32x4*)(out + (size_t)tok * ND + c0) = o4;
        }
    }
}

// ---------------------------------------------------------------------------
// Flash cross-attention, all-global frag-major K/V/Q, NO barriers, NO K/V
// LDS. Grid (NS/128, H, B), 4 waves, wave owns 32 q (qt=2). P crosses
// C->B layout via per-wave LDS (within-wave lgkmcnt ordering only).
// Scale prefolded in Q; additive mask bias; no running max (exact).
// Epilogue writes ctx frag-major for MLP0.
// ---------------------------------------------------------------------------
__global__ __launch_bounds__(256, 2) void attn_frag(
    const ushort_t* __restrict__ qF, const ushort_t* __restrict__ kF,
    const ushort_t* __restrict__ vF, const float* __restrict__ mbias,
    ushort_t* __restrict__ ctxF)
{
    __shared__ ushort_t Pl[8][16 * PITCH];

    const int t = threadIdx.x, w = t >> 6, lane = t & 63;
    const int lq = t & 15, lg = lane >> 4;
    const int qb = blockIdx.x, h = blockIdx.y, b = blockIdx.z;
    const int bh = b * NH + h;

    const ushort_t* qh = qF + (size_t)bh * 131072;
    const ushort_t* kh = kF + (size_t)bh * 131072;
    const ushort_t* vh = vF + (size_t)bh * 131072;
    const float* mrow = mbias + b * NS;
    const int qrow0 = qb * 128 + w * 32;
    const int q16 = qrow0 >> 4;

    bf16x8 qf[2][2];
#pragma unroll
    for (int qt = 0; qt < 2; qt++)
#pragma unroll
        for (int kc = 0; kc < 2; kc++)
            qf[qt][kc] = *(const bf16x8*)(qh + ((size_t)((q16 + qt) * 2 + kc) * 64 + lane) * 8);

    f32x4 o[2][4];
#pragma unroll
    for (int qt = 0; qt < 2; qt++)
#pragma unroll
        for (int dt = 0; dt < 4; dt++) o[qt][dt] = (f32x4){0.f, 0.f, 0.f, 0.f};
    float l_run[2] = {0.0f, 0.0f};

    for (int key0 = 0; key0 < NS; key0 += 64) {
        // K fragments direct from global (L2-resident)
        bf16x8 ka[4][2];
#pragma unroll
        for (int kt = 0; kt < 4; kt++)
#pragma unroll
            for (int kk = 0; kk < 2; kk++)
                ka[kt][kk] = *(const bf16x8*)(kh +
                    ((size_t)(((key0 >> 4) + kt) * 2 + kk) * 64 + lane) * 8);
        f32x4 mb[4];
#pragma unroll
        for (int kt = 0; kt < 4; kt++)
            mb[kt] = *(const f32x4*)(mrow + key0 + kt * 16 + lg * 4);

#pragma unroll
        for (int qt = 0; qt < 2; qt++) {
            f32x4 st[4];
#pragma unroll
            for (int kt = 0; kt < 4; kt++) {
                f32x4 a = (f32x4){0.f, 0.f, 0.f, 0.f};
                a = MFMA16(ka[kt][0], qf[qt][0], a);
                a = MFMA16(ka[kt][1], qf[qt][1], a);
                st[kt] = a;
            }
            float ls = 0.0f;
#pragma unroll
            for (int kt = 0; kt < 4; kt++) {
                float pr[4];
#pragma unroll
                for (int r = 0; r < 4; r++) {
                    const float p = exp2f(st[kt][r] + mb[kt][r]);
                    ls += p;
                    pr[r] = p;
                }
                uint2 pv;
                pv.x = pack2bf(pr[0], pr[1]);
                pv.y = pack2bf(pr[2], pr[3]);
                *(uint2*)&Pl[w * 2 + qt][lq * PITCH + kt * 16 + lg * 4] = pv;
            }
            ls += __shfl_xor(ls, 16);
            ls += __shfl_xor(ls, 32);
            l_run[qt] += ls;
        }

        bf16x8 pf[2][2];
#pragma unroll
        for (int qt = 0; qt < 2; qt++)
#pragma unroll
            for (int kh2 = 0; kh2 < 2; kh2++)
                pf[qt][kh2] = *(const bf16x8*)&Pl[w * 2 + qt][lq * PITCH + kh2 * 32 + lg * 8];

        // ctx^T += V^T·P ; V^T fragments direct from global
#pragma unroll
        for (int dt = 0; dt < 4; dt++)
#pragma unroll
            for (int kh2 = 0; kh2 < 2; kh2++) {
                bf16x8 vf = *(const bf16x8*)(vh +
                    ((size_t)(dt * 64 + (key0 >> 5) + kh2) * 64 + lane) * 8);
#pragma unroll
                for (int qt = 0; qt < 2; qt++)
                    o[qt][dt] = MFMA16(vf, pf[qt][kh2], o[qt][dt]);
            }
    }

    // epilogue: normalize, write ctx frag-major (C=256)
#pragma unroll
    for (int qt = 0; qt < 2; qt++) {
        const float li = 1.0f / l_run[qt];
        const int tok16 = b * 128 + q16 + qt;
#pragma unroll
        for (int dt = 0; dt < 4; dt++) {
            const int c = h * 64 + dt * 16 + lg * 4;
            uint2 pv;
            pv.x = pack2bf(o[qt][dt][0] * li, o[qt][dt][1] * li);
            pv.y = pack2bf(o[qt][dt][2] * li, o[qt][dt][3] * li);
            const size_t e = ((size_t)(tok16 * 8 + (c >> 5)) * 64 +
                              (((c >> 3) & 3) * 16 + lq)) * 8 + (c & 7);
            *(uint2*)(ctxF + e) = pv;
        }
    }
}

extern "C" void kernel_launch(void* const* d_in, const int* in_sizes, int n_in,
                              void* d_out, int out_size, void* d_ws, size_t ws_size,
                              hipStream_t stream)
{
    (void)in_sizes; (void)n_in; (void)out_size; (void)ws_size;
    const float* desc = (const float*)d_in[0];
    const float* srcp = (const float*)d_in[1];
    const int*   mask = (const int*)d_in[2];
    const float* q_w  = (const float*)d_in[3];
    const float* q_b  = (const float*)d_in[4];
    const float* k_w  = (const float*)d_in[5];
    const float* k_b  = (const float*)d_in[6];
    const float* v_w  = (const float*)d_in[7];
    const float* v_b  = (const float*)d_in[8];
    const float* o_w  = (const float*)d_in[9];
    const float* o_b  = (const float*)d_in[10];
    const float* m0_w = (const float*)d_in[11];
    const float* m0_b = (const float*)d_in[12];
    const float* bng  = (const float*)d_in[13];
    const float* bnb  = (const float*)d_in[14];
    const float* bnm  = (const float*)d_in[15];
    const float* bnv  = (const float*)d_in[16];
    const float* m1_w = (const float*)d_in[17];
    const float* m1_b = (const float*)d_in[18];
    float* out = (float*)d_out;

    // ws (~43 MB): 5 frag act buffers + frag weights
    const size_t ASZ = (size_t)NM * ND;  // 4,194,304 elems
    ushort_t* descF = (ushort_t*)d_ws;
    ushort_t* srcF  = descF + ASZ;
    ushort_t* qF    = descF + 2 * ASZ;
    ushort_t* kF    = descF + 3 * ASZ;
    ushort_t* vF    = descF + 4 * ASZ;
    ushort_t* qwF   = descF + 5 * ASZ;           // 65536
    ushort_t* kwF   = qwF + 65536;
    ushort_t* vwF   = kwF + 65536;
    ushort_t* m1F   = vwF + 65536;               // 131072
    ushort_t* m0fF  = m1F + 131072;              // 262144
    float*    biasf = (float*)(m0fF + 262144);   // 512
    float*    mbias = biasf + 512;               // 16384
    ushort_t* ctxF  = srcF;   // src dead after QKV
    ushort_t* hF    = qF;     // q+k dead after attention (2*ASZ span)

    const dim3 blk(256);

    conv_frag<<<dim3(2048, 2), blk, 0, stream>>>(desc, srcp, descF, srcF);
    wfrag<<<dim3(64, 4), blk, 0, stream>>>(q_w, k_w, v_w, m1_w, qwF, kwF, vwF, m1F);
    fuse_w<<<dim3(512), blk, 0, stream>>>(o_w, o_b, m0_w, m0_b,
                                          bng, bnb, bnm, bnv, m0fF, biasf);
    make_mbias<<<dim3(64), blk, 0, stream>>>(mask, mbias);

    qkv_frag<<<dim3(4, NM / 128, 3), blk, 0, stream>>>(
        descF, srcF, qwF, kwF, vwF, q_b, k_b, v_b, qF, kF, vF);
    attn_frag<<<dim3(NS / 128, NH, NB), blk, 0, stream>>>(qF, kF, vF, mbias, ctxF);
    mlp0_frag<<<dim3(8, NM / 128), blk, 0, stream>>>(descF, ctxF, m0fF, biasf, hF);
    mlp1_frag<<<dim3(4, NM / 128), blk, 0, stream>>>(hF, m1F, m1_b, out);
}

// Round 8
// 245.221 us; speedup vs baseline: 1.3428x; 1.2418x over previous
//
#include <hip/hip_runtime.h>

#define NB 8
#define NS 2048
#define ND 256
#define NH 4
#define NHD 64
#define ND2 512
#define NM (NB * NS)
#define PITCH 72            // padded LDS row pitch for Pl (bf16 elems)
#define C1 0.18033688f      // 0.125 * log2(e), prefolded into Q weights/bias

typedef __attribute__((ext_vector_type(8))) short          bf16x8;
typedef __attribute__((ext_vector_type(4))) float          f32x4;
typedef unsigned short ushort_t;
typedef unsigned int   uint_t;

#define MFMA16(a, b, c) __builtin_amdgcn_mfma_f32_16x16x32_bf16(a, b, c, 0, 0, 0)

#if __has_builtin(__builtin_amdgcn_exp2f)
#define EXP2(x) __builtin_amdgcn_exp2f(x)
#else
#define EXP2(x) exp2f(x)
#endif

static __device__ inline uint_t pack2bf(float a, float b) {
    union { float f; uint_t u; } x, y; x.f = a; y.f = b;
    return __builtin_amdgcn_perm(y.u + 0x8000u, x.u + 0x8000u, 0x07060302u);
}
static __device__ inline ushort_t f2bf(float f) {
    union { float f; uint_t u; } x; x.f = f;
    return (ushort_t)((x.u + 0x7FFFu + ((x.u >> 16) & 1u)) >> 16);
}

// ===========================================================================
// Fragment-major layout: matrix Mat[R][C] stored so the MFMA fragment
// (lane lq=l&15 holds Mat[r16*16+lq][kc*32+(l>>4)*8+j]) is one coalesced
// 16B/lane load: elem = ((r16*(C/32)+kc)*64 + lane)*8 + j.
// ===========================================================================

__global__ __launch_bounds__(256) void conv_frag(
    const float* __restrict__ d, const float* __restrict__ s,
    ushort_t* __restrict__ df, ushort_t* __restrict__ sf)
{
    const float* src = blockIdx.y ? s : d;
    ushort_t* dst    = blockIdx.y ? sf : df;
    const int g = blockIdx.x * 256 + threadIdx.x;
    const int lane = g & 63, ci = g >> 6;
    const int kc = ci & 7, r16 = ci >> 3;
    const int row = r16 * 16 + (lane & 15);
    const int c0  = kc * 32 + (lane >> 4) * 8;
    const float* p = src + (size_t)row * ND + c0;
    float4 a = *(const float4*)p;
    float4 b = *(const float4*)(p + 4);
    uint4 pk;
    pk.x = pack2bf(a.x, a.y); pk.y = pack2bf(a.z, a.w);
    pk.z = pack2bf(b.x, b.y); pk.w = pack2bf(b.z, b.w);
    *(uint4*)(dst + (size_t)g * 8) = pk;
}

__global__ __launch_bounds__(256) void wfrag(
    const float* q, const float* k, const float* v, const float* m1,
    ushort_t* qw, ushort_t* kw, ushort_t* vw, ushort_t* m1f)
{
    const float* src; ushort_t* dst; int K, N; float sc = 1.0f;
    switch (blockIdx.y) {
        case 0: src = q;  dst = qw;  K = 256; N = 256; sc = C1; break;
        case 1: src = k;  dst = kw;  K = 256; N = 256; break;
        case 2: src = v;  dst = vw;  K = 256; N = 256; break;
        default: src = m1; dst = m1f; K = 512; N = 256; break;
    }
    const int g = blockIdx.x * 256 + threadIdx.x;
    if (g >= (N * K) / 8) return;
    const int lane = g & 63, ci = g >> 6;
    const int lgck = (K == 512) ? 4 : 3;
    const int kc = ci & ((1 << lgck) - 1), n16 = ci >> lgck;
    const int n  = n16 * 16 + (lane & 15);
    const int k0 = kc * 32 + (lane >> 4) * 8;
    float f[8];
#pragma unroll
    for (int j = 0; j < 8; j++) f[j] = src[(size_t)(k0 + j) * N + n] * sc;
    uint4 pk;
    pk.x = pack2bf(f[0], f[1]); pk.y = pack2bf(f[2], f[3]);
    pk.z = pack2bf(f[4], f[5]); pk.w = pack2bf(f[6], f[7]);
    *(uint4*)(dst + (size_t)g * 8) = pk;
}

static __device__ inline void femit(ushort_t* buf, int n, int k, float v) {
    const int kc = k >> 5;
    const int lane = (((k >> 3) & 3) << 4) | (n & 15);
    const int j = k & 7;
    buf[((size_t)(((n >> 4) * 16 + kc) * 64 + lane)) * 8 + j] = f2bf(v);
}

__global__ __launch_bounds__(256) void fuse_w(
    const float* __restrict__ o_w, const float* __restrict__ o_b,
    const float* __restrict__ m0_w, const float* __restrict__ m0_b,
    const float* __restrict__ bng, const float* __restrict__ bnb,
    const float* __restrict__ bnm, const float* __restrict__ bnv,
    ushort_t* __restrict__ m0fF, float* __restrict__ biasf)
{
    __shared__ float red[256];
    const int n = blockIdx.x;
    const int i = threadIdx.x;
    const float A = bng[n] * rsqrtf(bnv[n] + 1e-5f);
    float f = 0.f;
#pragma unroll 8
    for (int j = 0; j < 256; j++)
        f += o_w[i * 256 + j] * m0_w[(size_t)(256 + j) * 512 + n];
    femit(m0fF, n, 256 + i, f * A);
    femit(m0fF, n, i, m0_w[(size_t)i * 512 + n] * A);
    red[i] = o_b[i] * m0_w[(size_t)(256 + i) * 512 + n];
    __syncthreads();
    for (int s = 128; s > 0; s >>= 1) {
        if (i < s) red[i] += red[i + s];
        __syncthreads();
    }
    if (i == 0) biasf[n] = (m0_b[n] + red[0] - bnm[n]) * A + bnb[n];
}

__global__ __launch_bounds__(256) void make_mbias(
    const int* __restrict__ mask, float* __restrict__ mb)
{
    const int i = blockIdx.x * 256 + threadIdx.x;
    mb[i] = mask[i] ? 0.0f : -1e9f;
}

// ---------------------------------------------------------------------------
// GEMM core, register-blocked: wave-tile 64 tok x 64 ch (4x4 MFMA per kc,
// 8 frag loads per 16 MFMA). All-global frag-major, no LDS, no barriers.
// ---------------------------------------------------------------------------
template <int KC, int AK, bool NAT>
static __device__ inline void core4(
    const ushort_t* __restrict__ A0, const ushort_t* __restrict__ A1,
    const ushort_t* __restrict__ WF, int t16, int n16, f32x4 acc[4][4])
{
    const int lane = threadIdx.x & 63;
#pragma unroll
    for (int kc = 0; kc < KC; kc++) {
        const ushort_t* Ab = (kc < AK) ? A0 : A1;
        const int kca = (kc < AK) ? kc : kc - AK;
        bf16x8 af[4], wf[4];
#pragma unroll
        for (int mt = 0; mt < 4; mt++)
            af[mt] = *(const bf16x8*)(Ab + ((size_t)((t16 + mt) * AK + kca) * 64 + lane) * 8);
#pragma unroll
        for (int nt = 0; nt < 4; nt++)
            wf[nt] = *(const bf16x8*)(WF + ((size_t)((n16 + nt) * KC + kc) * 64 + lane) * 8);
#pragma unroll
        for (int mt = 0; mt < 4; mt++)
#pragma unroll
            for (int nt = 0; nt < 4; nt++) {
                if (NAT) acc[mt][nt] = MFMA16(af[mt], wf[nt], acc[mt][nt]);
                else     acc[mt][nt] = MFMA16(wf[nt], af[mt], acc[mt][nt]);
            }
    }
}

// ---------------------------------------------------------------------------
// fused QKV. grid (4 heads, NM/256, 3); 4 waves t-split (wave 64 tok x 64 ch)
// ---------------------------------------------------------------------------
__global__ __launch_bounds__(256) void qkv_frag(
    const ushort_t* __restrict__ descF, const ushort_t* __restrict__ srcF,
    const ushort_t* __restrict__ qwF, const ushort_t* __restrict__ kwF,
    const ushort_t* __restrict__ vwF,
    const float* __restrict__ q_b, const float* __restrict__ k_b,
    const float* __restrict__ v_b,
    ushort_t* __restrict__ qF, ushort_t* __restrict__ kF,
    ushort_t* __restrict__ vF)
{
    const int t = threadIdx.x, w = t >> 6;
    const int lq = t & 15, lg = (t & 63) >> 4;
    const int h    = blockIdx.x;
    const int tok0 = (blockIdx.y << 8) + (w << 6);
    const int t16  = tok0 >> 4, n16 = h << 2;
    const int z    = blockIdx.z;

    f32x4 acc[4][4];
#pragma unroll
    for (int mt = 0; mt < 4; mt++)
#pragma unroll
        for (int nt = 0; nt < 4; nt++) acc[mt][nt] = (f32x4){0.f, 0.f, 0.f, 0.f};

    if (z == 2) {
        core4<8, 8, true>(srcF, srcF, vwF, t16, n16, acc);
#pragma unroll
        for (int nt = 0; nt < 4; nt++) {
            const int dvh = nt * 16 + lq;
            const float bs = v_b[h * 64 + dvh];
#pragma unroll
            for (int mt = 0; mt < 4; mt++) {
                const int tok = tok0 + mt * 16 + lg * 4;
                const int b = tok >> 11, s0 = tok & 2047;
                const int bh = b * NH + h;
                uint2 pv;
                pv.x = pack2bf(acc[mt][nt][0] + bs, acc[mt][nt][1] + bs);
                pv.y = pack2bf(acc[mt][nt][2] + bs, acc[mt][nt][3] + bs);
                const size_t e = (size_t)bh * 131072 +
                    ((size_t)((dvh >> 4) * 64 + (s0 >> 5)) * 64 +
                     (((s0 >> 3) & 3) * 16 + (dvh & 15))) * 8 + (s0 & 7);
                *(uint2*)(vF + e) = pv;
            }
        }
    } else {
        const ushort_t* A = z ? srcF : descF;
        const ushort_t* W = z ? kwF : qwF;
        const float* bias = z ? k_b : q_b;
        ushort_t* dst     = z ? kF : qF;
        const float bsc   = z ? 1.0f : C1;
        core4<8, 8, false>(A, A, W, t16, n16, acc);
#pragma unroll
        for (int nt = 0; nt < 4; nt++) {
            const int d0 = nt * 16 + lg * 4;
            f32x4 b4 = *(const f32x4*)(bias + h * 64 + d0);
#pragma unroll
            for (int mt = 0; mt < 4; mt++) {
                const int tok = tok0 + mt * 16 + lq;
                const int b = tok >> 11, s = tok & 2047;
                const int bh = b * NH + h;
                uint2 pv;
                pv.x = pack2bf(acc[mt][nt][0] + b4[0] * bsc,
                               acc[mt][nt][1] + b4[1] * bsc);
                pv.y = pack2bf(acc[mt][nt][2] + b4[2] * bsc,
                               acc[mt][nt][3] + b4[3] * bsc);
                const size_t e = (size_t)bh * 131072 +
                    ((size_t)((s >> 4) * 2 + (d0 >> 5)) * 64 +
                     (((d0 >> 3) & 3) * 16 + lq)) * 8 + (d0 & 7);
                *(uint2*)(dst + e) = pv;
            }
        }
    }
}

// ---------------------------------------------------------------------------
// MLP0 (out-proj+BN fused): h = relu([desc|ctx]@m0f + biasf). grid (8, NM/256)
// ---------------------------------------------------------------------------
__global__ __launch_bounds__(256) void mlp0_frag(
    const ushort_t* __restrict__ descF, const ushort_t* __restrict__ ctxF,
    const ushort_t* __restrict__ m0fF, const float* __restrict__ biasf,
    ushort_t* __restrict__ hF)
{
    const int t = threadIdx.x, w = t >> 6;
    const int lq = t & 15, lg = (t & 63) >> 4;
    const int n0   = blockIdx.x << 6;
    const int tok0 = (blockIdx.y << 8) + (w << 6);
    const int t16  = tok0 >> 4, n16 = n0 >> 4;

    f32x4 acc[4][4];
#pragma unroll
    for (int mt = 0; mt < 4; mt++)
#pragma unroll
        for (int nt = 0; nt < 4; nt++) acc[mt][nt] = (f32x4){0.f, 0.f, 0.f, 0.f};

    core4<16, 8, false>(descF, ctxF, m0fF, t16, n16, acc);

#pragma unroll
    for (int nt = 0; nt < 4; nt++) {
        const int c0 = n0 + nt * 16 + lg * 4;
        f32x4 b4 = *(const f32x4*)(biasf + c0);
#pragma unroll
        for (int mt = 0; mt < 4; mt++) {
            const int tok = tok0 + mt * 16 + lq;
            uint2 pv;
            pv.x = pack2bf(fmaxf(acc[mt][nt][0] + b4[0], 0.f),
                           fmaxf(acc[mt][nt][1] + b4[1], 0.f));
            pv.y = pack2bf(fmaxf(acc[mt][nt][2] + b4[2], 0.f),
                           fmaxf(acc[mt][nt][3] + b4[3], 0.f));
            const size_t e = ((size_t)((tok >> 4) * 16 + (c0 >> 5)) * 64 +
                              (((c0 >> 3) & 3) * 16 + lq)) * 8 + (c0 & 7);
            *(uint2*)(hF + e) = pv;
        }
    }
}

// ---------------------------------------------------------------------------
// MLP1: out = hF @ m1 + m1_b, fp32 row-major. grid (4, NM/256).
// ---------------------------------------------------------------------------
__global__ __launch_bounds__(256) void mlp1_frag(
    const ushort_t* __restrict__ hF, const ushort_t* __restrict__ m1F,
    const float* __restrict__ m1_b, float* __restrict__ out)
{
    const int t = threadIdx.x, w = t >> 6;
    const int lq = t & 15, lg = (t & 63) >> 4;
    const int n0   = blockIdx.x << 6;
    const int tok0 = (blockIdx.y << 8) + (w << 6);
    const int t16  = tok0 >> 4, n16 = n0 >> 4;

    f32x4 acc[4][4];
#pragma unroll
    for (int mt = 0; mt < 4; mt++)
#pragma unroll
        for (int nt = 0; nt < 4; nt++) acc[mt][nt] = (f32x4){0.f, 0.f, 0.f, 0.f};

    core4<16, 16, false>(hF, hF, m1F, t16, n16, acc);

#pragma unroll
    for (int nt = 0; nt < 4; nt++) {
        const int c0 = n0 + nt * 16 + lg * 4;
        f32x4 b4 = *(const f32x4*)(m1_b + c0);
#pragma unroll
        for (int mt = 0; mt < 4; mt++) {
            const int tok = tok0 + mt * 16 + lq;
            f32x4 o4;
#pragma unroll
            for (int j = 0; j < 4; j++) o4[j] = acc[mt][nt][j] + b4[j];
            *(f32x4*)(out + (size_t)tok * ND + c0) = o4;
        }
    }
}

// ---------------------------------------------------------------------------
// Flash cross-attention v4: frag-major global K/V/Q, no barriers, software-
// pipelined. Per 64-key chunk: V frags issued at iteration TOP (consumed
// after softmax -> latency hidden), K frags for chunk i+1 prefetched after
// QK MFMAs (wrap-indexed, branchless). Raw v_exp_f32; deferred l-reduction.
// Grid (NS/128, H, B) = 512 blocks, 4 waves, wave owns 32 q (qt=2).
// ---------------------------------------------------------------------------
__global__ __launch_bounds__(256) void attn_frag(
    const ushort_t* __restrict__ qF, const ushort_t* __restrict__ kF,
    const ushort_t* __restrict__ vF, const float* __restrict__ mbias,
    ushort_t* __restrict__ ctxF)
{
    __shared__ ushort_t Pl[8][16 * PITCH];

    const int t = threadIdx.x, w = t >> 6, lane = t & 63;
    const int lq = t & 15, lg = lane >> 4;
    const int qb = blockIdx.x, h = blockIdx.y, b = blockIdx.z;
    const int bh = b * NH + h;

    const ushort_t* qh = qF + (size_t)bh * 131072;
    const ushort_t* kh = kF + (size_t)bh * 131072;
    const ushort_t* vh = vF + (size_t)bh * 131072;
    const float* mrow = mbias + b * NS;
    const int qrow0 = qb * 128 + w * 32;
    const int q16 = qrow0 >> 4;

    bf16x8 qf[2][2];
#pragma unroll
    for (int qt = 0; qt < 2; qt++)
#pragma unroll
        for (int kc = 0; kc < 2; kc++)
            qf[qt][kc] = *(const bf16x8*)(qh + ((size_t)((q16 + qt) * 2 + kc) * 64 + lane) * 8);

    f32x4 o[2][4];
#pragma unroll
    for (int qt = 0; qt < 2; qt++)
#pragma unroll
        for (int dt = 0; dt < 4; dt++) o[qt][dt] = (f32x4){0.f, 0.f, 0.f, 0.f};
    float l_part[2] = {0.0f, 0.0f};

    // preload K frags for chunk 0
    bf16x8 ka[4][2];
#pragma unroll
    for (int kt = 0; kt < 4; kt++)
#pragma unroll
        for (int kk = 0; kk < 2; kk++)
            ka[kt][kk] = *(const bf16x8*)(kh + ((size_t)((kt * 2 + kk) * 64 + lane)) * 8);

    for (int key0 = 0; key0 < NS; key0 += 64) {
        // V fragments for THIS chunk: issue now, consumed after softmax
        bf16x8 vf[4][2];
        const ushort_t* vb = vh + (size_t)(key0 >> 5) * 512;
#pragma unroll
        for (int dt = 0; dt < 4; dt++)
#pragma unroll
            for (int kh2 = 0; kh2 < 2; kh2++)
                vf[dt][kh2] = *(const bf16x8*)(vb +
                    ((size_t)((dt * 64 + kh2) * 64 + lane)) * 8);
        f32x4 mb[4];
#pragma unroll
        for (int kt = 0; kt < 4; kt++)
            mb[kt] = *(const f32x4*)(mrow + key0 + kt * 16 + lg * 4);

        // QK: S^T[key][q] for both q-tiles (C-layout: col = q = lq)
        f32x4 st[2][4];
#pragma unroll
        for (int qt = 0; qt < 2; qt++)
#pragma unroll
            for (int kt = 0; kt < 4; kt++) {
                f32x4 a = (f32x4){0.f, 0.f, 0.f, 0.f};
                a = MFMA16(ka[kt][0], qf[qt][0], a);
                a = MFMA16(ka[kt][1], qf[qt][1], a);
                st[qt][kt] = a;
            }

        // prefetch next chunk's K frags (wrap to stay in-bounds, branchless)
        const int keyn = (key0 + 64) & (NS - 1);
        const ushort_t* kb = kh + (size_t)keyn * 64;
        bf16x8 kn[4][2];
#pragma unroll
        for (int kt = 0; kt < 4; kt++)
#pragma unroll
            for (int kk = 0; kk < 2; kk++)
                kn[kt][kk] = *(const bf16x8*)(kb + ((size_t)((kt * 2 + kk) * 64 + lane)) * 8);

        // softmax numerator + P pack (no max-subtract: scores bounded)
#pragma unroll
        for (int qt = 0; qt < 2; qt++) {
            float ls = 0.0f;
#pragma unroll
            for (int kt = 0; kt < 4; kt++) {
                float pr[4];
#pragma unroll
                for (int r = 0; r < 4; r++) {
                    const float p = EXP2(st[qt][kt][r] + mb[kt][r]);
                    ls += p;
                    pr[r] = p;
                }
                uint2 pv;
                pv.x = pack2bf(pr[0], pr[1]);
                pv.y = pack2bf(pr[2], pr[3]);
                *(uint2*)&Pl[w * 2 + qt][lq * PITCH + kt * 16 + lg * 4] = pv;
            }
            l_part[qt] += ls;   // per-lane partial; reduced once at the end
        }

        bf16x8 pf[2][2];
#pragma unroll
        for (int qt = 0; qt < 2; qt++)
#pragma unroll
            for (int kh2 = 0; kh2 < 2; kh2++)
                pf[qt][kh2] = *(const bf16x8*)&Pl[w * 2 + qt][lq * PITCH + kh2 * 32 + lg * 8];

        // ctx^T += V^T·P using the V frags issued at iteration top
#pragma unroll
        for (int dt = 0; dt < 4; dt++)
#pragma unroll
            for (int kh2 = 0; kh2 < 2; kh2++)
#pragma unroll
                for (int qt = 0; qt < 2; qt++)
                    o[qt][dt] = MFMA16(vf[dt][kh2], pf[qt][kh2], o[qt][dt]);

        // rotate K double-buffer
#pragma unroll
        for (int kt = 0; kt < 4; kt++)
#pragma unroll
            for (int kk = 0; kk < 2; kk++)
                ka[kt][kk] = kn[kt][kk];
    }

    // final l reduction (sum over lane-groups) + epilogue
#pragma unroll
    for (int qt = 0; qt < 2; qt++) {
        float ls = l_part[qt];
        ls += __shfl_xor(ls, 16);
        ls += __shfl_xor(ls, 32);
        const float li = 1.0f / ls;
        const int tok16 = b * 128 + q16 + qt;
#pragma unroll
        for (int dt = 0; dt < 4; dt++) {
            const int c = h * 64 + dt * 16 + lg * 4;
            uint2 pv;
            pv.x = pack2bf(o[qt][dt][0] * li, o[qt][dt][1] * li);
            pv.y = pack2bf(o[qt][dt][2] * li, o[qt][dt][3] * li);
            const size_t e = ((size_t)(tok16 * 8 + (c >> 5)) * 64 +
                              (((c >> 3) & 3) * 16 + lq)) * 8 + (c & 7);
            *(uint2*)(ctxF + e) = pv;
        }
    }
}

extern "C" void kernel_launch(void* const* d_in, const int* in_sizes, int n_in,
                              void* d_out, int out_size, void* d_ws, size_t ws_size,
                              hipStream_t stream)
{
    (void)in_sizes; (void)n_in; (void)out_size; (void)ws_size;
    const float* desc = (const float*)d_in[0];
    const float* srcp = (const float*)d_in[1];
    const int*   mask = (const int*)d_in[2];
    const float* q_w  = (const float*)d_in[3];
    const float* q_b  = (const float*)d_in[4];
    const float* k_w  = (const float*)d_in[5];
    const float* k_b  = (const float*)d_in[6];
    const float* v_w  = (const float*)d_in[7];
    const float* v_b  = (const float*)d_in[8];
    const float* o_w  = (const float*)d_in[9];
    const float* o_b  = (const float*)d_in[10];
    const float* m0_w = (const float*)d_in[11];
    const float* m0_b = (const float*)d_in[12];
    const float* bng  = (const float*)d_in[13];
    const float* bnb  = (const float*)d_in[14];
    const float* bnm  = (const float*)d_in[15];
    const float* bnv  = (const float*)d_in[16];
    const float* m1_w = (const float*)d_in[17];
    const float* m1_b = (const float*)d_in[18];
    float* out = (float*)d_out;

    const size_t ASZ = (size_t)NM * ND;
    ushort_t* descF = (ushort_t*)d_ws;
    ushort_t* srcF  = descF + ASZ;
    ushort_t* qF    = descF + 2 * ASZ;
    ushort_t* kF    = descF + 3 * ASZ;
    ushort_t* vF    = descF + 4 * ASZ;
    ushort_t* qwF   = descF + 5 * ASZ;
    ushort_t* kwF   = qwF + 65536;
    ushort_t* vwF   = kwF + 65536;
    ushort_t* m1F   = vwF + 65536;
    ushort_t* m0fF  = m1F + 131072;
    float*    biasf = (float*)(m0fF + 262144);
    float*    mbias = biasf + 512;
    ushort_t* ctxF  = srcF;   // src dead after QKV
    ushort_t* hF    = qF;     // q+k dead after attention

    const dim3 blk(256);

    conv_frag<<<dim3(2048, 2), blk, 0, stream>>>(desc, srcp, descF, srcF);
    wfrag<<<dim3(64, 4), blk, 0, stream>>>(q_w, k_w, v_w, m1_w, qwF, kwF, vwF, m1F);
    fuse_w<<<dim3(512), blk, 0, stream>>>(o_w, o_b, m0_w, m0_b,
                                          bng, bnb, bnm, bnv, m0fF, biasf);
    make_mbias<<<dim3(64), blk, 0, stream>>>(mask, mbias);

    qkv_frag<<<dim3(4, NM / 256, 3), blk, 0, stream>>>(
        descF, srcF, qwF, kwF, vwF, q_b, k_b, v_b, qF, kF, vF);
    attn_frag<<<dim3(NS / 128, NH, NB), blk, 0, stream>>>(qF, kF, vF, mbias, ctxF);
    mlp0_frag<<<dim3(8, NM / 256), blk, 0, stream>>>(descF, ctxF, m0fF, biasf, hF);
    mlp1_frag<<<dim3(4, NM / 256), blk, 0, stream>>>(hF, m1F, m1_b, out);
}